// Round 4
// baseline (140.362 us; speedup 1.0000x reference)
//
#include <hip/hip_runtime.h>

// RankingLoss: B=16384 rows, D=512 f32, L=14 labels.
// Per row i (j=i+1 mod B):
//   paired  = dot(zi[i], zt[i])
//   imp_img = dot(zi[j], zt[i])
//   imp_txt = dot(zt[j], zi[i])
//   margin  = all-equal? 0 : max(0.5, xor_cnt / or_cnt)
//   loss   += relu(imp_img - paired + margin) + relu(imp_txt - paired + margin)
// out[0] = loss / B
//
// v4: same main loop as v3 (split-D, register-carry strips, R=8). The
// separate 1-block reduce kernel (launch-latency dominated) is FUSED via a
// last-block ticket: each block release-stores (agent scope) its partial to
// ws[blockIdx.x] and acq_rel-increments a counter; the unique last block
// acquire-loads all partials and writes out[0]. Agent-scope atomics bypass
// the non-coherent per-XCD L2s, so no cross-XCD staleness / false-sharing
// writeback hazard. Only extra dispatch: a 4-byte memset of the counter.

constexpr int B = 16384;
constexpr int L = 14;
constexpr int BLOCK = 256;                  // 4 waves: 2 strips x 2 halves
constexpr int R = 8;                        // rows per strip
constexpr int STRIPS_PER_BLOCK = 2;
constexpr int GRID = B / (STRIPS_PER_BLOCK * R);   // 1024 blocks

__device__ __forceinline__ float dot4(float4 a, float4 b) {
    return a.x * b.x + a.y * b.y + a.z * b.z + a.w * b.w;
}

__global__ __launch_bounds__(BLOCK) void rank_fused(
    const float* __restrict__ zi, const float* __restrict__ zt,
    const int* __restrict__ labels, float* __restrict__ ws,
    unsigned int* __restrict__ counter, float* __restrict__ out)
{
    const int lane = threadIdx.x & 63;
    const int wv   = threadIdx.x >> 6;      // 0..3
    const int pair = wv >> 1;               // strip within block
    const int half = wv & 1;                // which 256-col half of D
    const int base = (blockIdx.x * STRIPS_PER_BLOCK + pair) * R;

    const float4* zi4 = (const float4*)zi;
    const float4* zt4 = (const float4*)zt;

    __shared__ float sdot[4][R][3];         // per-wave, per-row half-sums
    __shared__ float smar[STRIPS_PER_BLOCK][R];

    // Current row registers: 1 float4 per matrix (this wave's half of D).
    size_t o = (size_t)base * 128 + half * 64 + lane;
    float4 a = zi4[o];
    float4 b = zt4[o];
    int lab = (half == 0 && lane < L) ? labels[base * L + lane] : 0;
    float pd = dot4(a, b);                  // lane-partial paired(current)

    #pragma unroll
    for (int r = 0; r < R; ++r) {
        const int nrow = (base + r + 1) & (B - 1);
        const size_t no = (size_t)nrow * 128 + half * 64 + lane;
        const float4 na = zi4[no];
        const float4 nb = zt4[no];
        const int nlab = (half == 0 && lane < L) ? labels[nrow * L + lane] : 0;

        float s0 = pd;                      // dot(zi[i], zt[i]) partial
        float s1 = dot4(na, b);             // dot(zi[j], zt[i]) partial
        float s2 = dot4(nb, a);             // dot(zt[j], zi[i]) partial
        const float npd = dot4(na, nb);     // next paired, carried

        // Margin from label ballots (half-0 waves; lanes >= L contribute 0).
        if (half == 0) {
            const unsigned long long bor  = __ballot((lab | nlab) != 0);
            const unsigned long long bxor = __ballot((lab ^ nlab) != 0);
            if (lane == 0) {
                const int df = __popcll(bxor);
                float margin = 0.0f;
                if (df != 0)
                    margin = fmaxf(0.5f, (float)df / (float)__popcll(bor));
                smar[pair][r] = margin;
            }
        }

        // Wave-wide reduce of the three partials.
        #pragma unroll
        for (int off = 32; off > 0; off >>= 1) {
            s0 += __shfl_down(s0, off);
            s1 += __shfl_down(s1, off);
            s2 += __shfl_down(s2, off);
        }
        if (lane == 0) {
            sdot[wv][r][0] = s0;
            sdot[wv][r][1] = s1;
            sdot[wv][r][2] = s2;
        }

        a = na; b = nb; lab = nlab; pd = npd;
    }

    __syncthreads();

    // 16 rows per block: thread t < 16 combines halves + computes hinge.
    const int t = threadIdx.x;
    float hinge = 0.0f;
    if (t < STRIPS_PER_BLOCK * R) {
        const int p = t >> 3, r = t & 7;
        const float q0 = sdot[p * 2][r][0] + sdot[p * 2 + 1][r][0];
        const float q1 = sdot[p * 2][r][1] + sdot[p * 2 + 1][r][1];
        const float q2 = sdot[p * 2][r][2] + sdot[p * 2 + 1][r][2];
        const float m  = smar[p][r];
        hinge = fmaxf(q1 - q0 + m, 0.0f) + fmaxf(q2 - q0 + m, 0.0f);
    }
    #pragma unroll
    for (int off = 8; off > 0; off >>= 1) hinge += __shfl_down(hinge, off);

    // --- Fused finish: last-block ticket reduce ---------------------------
    __shared__ unsigned int sticket;
    if (t == 0) {
        // Publish this block's partial (release, agent scope = bypasses the
        // non-coherent per-XCD L2s), then take a ticket.
        __hip_atomic_store(&ws[blockIdx.x], hinge,
                           __ATOMIC_RELEASE, __HIP_MEMORY_SCOPE_AGENT);
        sticket = __hip_atomic_fetch_add(counter, 1u,
                                         __ATOMIC_ACQ_REL, __HIP_MEMORY_SCOPE_AGENT);
    }
    __syncthreads();

    if (sticket == GRID - 1) {
        // Unique last block: reduce all 1024 partials.
        float v = 0.0f;
        #pragma unroll
        for (int k = 0; k < GRID / BLOCK; ++k)
            v += __hip_atomic_load(&ws[t + k * BLOCK],
                                   __ATOMIC_RELAXED, __HIP_MEMORY_SCOPE_AGENT);
        #pragma unroll
        for (int off = 32; off > 0; off >>= 1) v += __shfl_down(v, off);
        __shared__ float sfin[4];
        if ((t & 63) == 0) sfin[t >> 6] = v;
        __syncthreads();
        if (t == 0)
            out[0] = (sfin[0] + sfin[1] + sfin[2] + sfin[3]) * (1.0f / (float)B);
    }
}

extern "C" void kernel_launch(void* const* d_in, const int* in_sizes, int n_in,
                              void* d_out, int out_size, void* d_ws, size_t ws_size,
                              hipStream_t stream) {
    const float* zi     = (const float*)d_in[0];
    const float* zt     = (const float*)d_in[1];
    const int*   labels = (const int*)d_in[2];
    float* out = (float*)d_out;
    float* ws  = (float*)d_ws;                         // GRID partials
    unsigned int* counter = (unsigned int*)(ws + GRID); // 4-byte ticket

    hipMemsetAsync(counter, 0, sizeof(unsigned int), stream);
    rank_fused<<<GRID, BLOCK, 0, stream>>>(zi, zt, labels, ws, counter, out);
}

// Round 8
// 100.034 us; speedup vs baseline: 1.4031x; 1.4031x over previous
//
#include <hip/hip_runtime.h>

// RankingLoss: B=16384 rows, D=512 f32, L=14 labels.
// Per row i (j=i+1 mod B):
//   paired  = dot(zi[i], zt[i])
//   imp_img = dot(zi[j], zt[i])
//   imp_txt = dot(zt[j], zi[i])
//   margin  = all-equal? 0 : max(0.5, xor_cnt / or_cnt)
//   loss   += relu(imp_img - paired + margin) + relu(imp_txt - paired + margin)
// out[0] = loss / B
//
// v5 (3rd resubmit; rounds 5-7 hit GPUAcquisitionTimeout — no result):
//   - explicit one-ahead prefetch (fa/fb) so next row's loads overlap the
//     current row's shuffle-reduce chain (v3's VGPR=20 showed the compiler
//     serialized the loop)
//   - R=4 -> 2048 blocks -> 8 waves/SIMD (2x TLP; logical 160 MB, L3-resident)
//   - XCD-chunked block swizzle: consecutive strips on the same XCD so the
//     shared boundary row is an L2 hit (GRID % 8 == 0, bijective)

constexpr int B = 16384;
constexpr int L = 14;
constexpr int BLOCK = 256;                  // 4 waves: 2 strips x 2 halves
constexpr int R = 4;                        // rows per strip
constexpr int SPB = 2;                      // strips per block
constexpr int GRID = B / (SPB * R);         // 2048 blocks
constexpr int NXCD = 8;
constexpr int CPX = GRID / NXCD;            // 256 blocks per XCD chunk

__device__ __forceinline__ float dot4(float4 a, float4 b) {
    return a.x * b.x + a.y * b.y + a.z * b.z + a.w * b.w;
}

__global__ __launch_bounds__(BLOCK) void rank_main(
    const float* __restrict__ zi, const float* __restrict__ zt,
    const int* __restrict__ labels, float* __restrict__ ws)
{
    const int lane = threadIdx.x & 63;
    const int wv   = threadIdx.x >> 6;      // 0..3
    const int pair = wv >> 1;               // strip within block
    const int half = wv & 1;                // which 256-col half of D
    // XCD-chunked swizzle: HW round-robins blockIdx across 8 XCDs; remap so
    // XCD x owns contiguous strip range [x*CPX, (x+1)*CPX).
    const int bid  = (int)(blockIdx.x & (NXCD - 1)) * CPX + (int)(blockIdx.x >> 3);
    const int base = (bid * SPB + pair) * R;

    const float4* zi4 = (const float4*)zi;
    const float4* zt4 = (const float4*)zt;

    __shared__ float sdot[4][R][3];         // per-wave, per-row half-sums
    __shared__ float smar[SPB][R];

    const int col = half * 64 + lane;       // float4 column within row
    const size_t o = (size_t)base * 128 + col;

    // Current row (base) and next row (base+1) in registers.
    float4 a = zi4[o], b = zt4[o];
    const int r1 = (base + 1) & (B - 1);
    float4 na = zi4[(size_t)r1 * 128 + col];
    float4 nb = zt4[(size_t)r1 * 128 + col];
    int lab  = (half == 0 && lane < L) ? labels[base * L + lane] : 0;
    int nlab = (half == 0 && lane < L) ? labels[r1 * L + lane] : 0;
    float pd = dot4(a, b);                  // lane-partial paired(current)

    #pragma unroll
    for (int r = 0; r < R; ++r) {
        // Prefetch row base+r+2 (consumed next iteration) before the
        // dependent reduce chain of this iteration.
        float4 fa = make_float4(0.f, 0.f, 0.f, 0.f), fb = fa;
        int flab = 0;
        if (r < R - 1) {
            const int frow = (base + r + 2) & (B - 1);
            const size_t fo = (size_t)frow * 128 + col;
            fa = zi4[fo];
            fb = zt4[fo];
            if (half == 0 && lane < L) flab = labels[frow * L + lane];
        }

        float s0 = pd;                      // dot(zi[i], zt[i]) partial
        float s1 = dot4(na, b);             // dot(zi[j], zt[i]) partial
        float s2 = dot4(nb, a);             // dot(zt[j], zi[i]) partial
        const float npd = dot4(na, nb);     // next paired, carried

        if (half == 0) {
            const unsigned long long bor  = __ballot((lab | nlab) != 0);
            const unsigned long long bxor = __ballot((lab ^ nlab) != 0);
            if (lane == 0) {
                const int df = __popcll(bxor);
                float margin = 0.0f;
                if (df != 0)
                    margin = fmaxf(0.5f, (float)df / (float)__popcll(bor));
                smar[pair][r] = margin;
            }
        }

        #pragma unroll
        for (int off = 32; off > 0; off >>= 1) {
            s0 += __shfl_down(s0, off);
            s1 += __shfl_down(s1, off);
            s2 += __shfl_down(s2, off);
        }
        if (lane == 0) {
            sdot[wv][r][0] = s0;
            sdot[wv][r][1] = s1;
            sdot[wv][r][2] = s2;
        }

        a = na; b = nb; na = fa; nb = fb;
        lab = nlab; nlab = flab; pd = npd;
    }

    __syncthreads();

    // 8 rows per block: thread t < 8 combines halves + computes hinge.
    const int t = threadIdx.x;
    float hinge = 0.0f;
    if (t < SPB * R) {
        const int p = t >> 2, r = t & 3;
        const float q0 = sdot[p * 2][r][0] + sdot[p * 2 + 1][r][0];
        const float q1 = sdot[p * 2][r][1] + sdot[p * 2 + 1][r][1];
        const float q2 = sdot[p * 2][r][2] + sdot[p * 2 + 1][r][2];
        const float m  = smar[p][r];
        hinge = fmaxf(q1 - q0 + m, 0.0f) + fmaxf(q2 - q0 + m, 0.0f);
    }
    #pragma unroll
    for (int off = 4; off > 0; off >>= 1) hinge += __shfl_down(hinge, off);
    if (t == 0) ws[blockIdx.x] = hinge;
}

__global__ __launch_bounds__(BLOCK) void rank_reduce(
    const float* __restrict__ ws, float* __restrict__ out)
{
    // GRID (=2048) partials; 256 threads, 8 each.
    const int t = threadIdx.x;
    float v = 0.0f;
    #pragma unroll
    for (int k = 0; k < GRID / BLOCK; ++k) v += ws[t + k * BLOCK];
    #pragma unroll
    for (int off = 32; off > 0; off >>= 1) v += __shfl_down(v, off);
    __shared__ float s[4];
    if ((t & 63) == 0) s[t >> 6] = v;
    __syncthreads();
    if (t == 0)
        out[0] = (s[0] + s[1] + s[2] + s[3]) * (1.0f / (float)B);
}

extern "C" void kernel_launch(void* const* d_in, const int* in_sizes, int n_in,
                              void* d_out, int out_size, void* d_ws, size_t ws_size,
                              hipStream_t stream) {
    const float* zi     = (const float*)d_in[0];
    const float* zt     = (const float*)d_in[1];
    const int*   labels = (const int*)d_in[2];
    float* out = (float*)d_out;
    float* ws  = (float*)d_ws;

    rank_main<<<GRID, BLOCK, 0, stream>>>(zi, zt, labels, ws);
    rank_reduce<<<1, BLOCK, 0, stream>>>(ws, out);
}